// Round 16
// baseline (60.173 us; speedup 1.0000x reference)
//
#include <hip/hip_runtime.h>

typedef __attribute__((ext_vector_type(8))) short bf16x8;
typedef __attribute__((ext_vector_type(4))) float f32x4;
typedef __attribute__((ext_vector_type(8))) unsigned short u16x8;

__device__ __forceinline__ unsigned short f2bf(float f) {
  union { float f; unsigned u; } v; v.f = f;
  unsigned r = v.u + 0x7FFF + ((v.u >> 16) & 1);
  return (unsigned short)(r >> 16);
}
__device__ __forceinline__ float bf2f(unsigned short s) {
  union { unsigned u; float f; } v; v.u = ((unsigned)s) << 16;
  return v.f;
}
__device__ __forceinline__ void gll16(const unsigned short* g, unsigned short* l) {
  __builtin_amdgcn_global_load_lds(
      (const __attribute__((address_space(1))) void*)g,
      (__attribute__((address_space(3))) void*)l, 16, 0, 0);
}

// W[m][n][k] f32 -> Wt[m][k][n] bf16, 16B-chunk XOR swizzle: slot = g ^ (k&7)
__global__ __launch_bounds__(256) void transpose_w(const float* __restrict__ W1,
                                                   const float* __restrict__ W2,
                                                   unsigned short* __restrict__ W1t,
                                                   unsigned short* __restrict__ W2t) {
  __shared__ float ws_[64 * 64];
  const int m = blockIdx.x & 63, sel = blockIdx.x >> 6;
  const float* src = (sel ? W2 : W1) + m * 4096;
  unsigned short* dst = (sel ? W2t : W1t) + m * 4096;
  const int t = threadIdx.x;
  #pragma unroll
  for (int i = 0; i < 4; ++i) {
    const int idx = i * 256 + t;
    *(float4*)&ws_[idx << 2] = *(const float4*)&src[idx << 2];
  }
  __syncthreads();
  #pragma unroll
  for (int j = 0; j < 2; ++j) {
    const int idx = j * 256 + t;
    const int k = idx >> 3, g = idx & 7;
    u16x8 o;
    #pragma unroll
    for (int jj = 0; jj < 8; ++jj) o[jj] = f2bf(ws_[(((g << 3) + jj) << 6) + k]);
    const int slot = g ^ (k & 7);
    *(u16x8*)&dst[(k << 6) + (slot << 3)] = o;
  }
}

// One cross layer, k-split geometry:
// Out[b, kq*16 + kk, d] = relu( sum_m U[b,m,d] * (sum_n Wt[m][kq*16+kk][n] * x[b,n,d]) )
// Block = (kq, b, 128-d tile); 512 blocks (2/CU); 256 thr = 4 waves over d (32 each).
// W per block per layer = 64m x 16k x 64n x 2B = 128 KB (4x less than all-k blocks).
// W streamed in 8 chunks of 8 m-slices (16 KB) through a 2-buffer ping-pong.
// UF32=1: u = v = x (layer 1), u_lds aliases v_lds. UF32=0: u = X1kd bf16.
// LDS: wbuf[2][16KB] | v_lds[64][128] (16KB) | (UF32==0: u_lds[64][128] 16KB)
template <int UF32>
__global__ __launch_bounds__(256) void layer_k16(
    const unsigned short* __restrict__ Ubf, const float* __restrict__ x,
    const unsigned short* __restrict__ Wt, unsigned short* __restrict__ Okd) {
  extern __shared__ char smem[];
  unsigned short* wbuf = (unsigned short*)smem;                // 2 * 8192 shorts
  unsigned short* v_lds = (unsigned short*)(smem + 32768);     // [n][128]
  unsigned short* u_lds = UF32 ? v_lds : (unsigned short*)(smem + 49152);

  const int t = threadIdx.x;
  const int l = t & 63, dw = t >> 6;           // wave covers d cols dw*32..+31
  const int id = blockIdx.x;
  const int kq = id & 3;                       // k-quarter (16 rows)
  const int b = (id >> 2) & 31;
  const int d0 = (id >> 7) << 7;               // 128-d tile
  const int l15 = l & 15, lg = l >> 4;

  // stage v = bf16(x[b, n, d0..d0+127]) -> v_lds[n][128]; thread: row n = t>>2,
  // cols seg*32..+31 (seg = t&3).
  {
    const int n = t >> 2, seg = t & 3;
    const float* src = x + ((b << 6) + n) * 512 + d0 + (seg << 5);
    unsigned short* dst = v_lds + (n << 7) + (seg << 5);
    #pragma unroll
    for (int q = 0; q < 4; ++q) {
      float4 a = *(const float4*)(src + q * 8);
      float4 c4 = *(const float4*)(src + q * 8 + 4);
      u16x8 o;
      o[0] = f2bf(a.x); o[1] = f2bf(a.y); o[2] = f2bf(a.z); o[3] = f2bf(a.w);
      o[4] = f2bf(c4.x); o[5] = f2bf(c4.y); o[6] = f2bf(c4.z); o[7] = f2bf(c4.w);
      *(u16x8*)(dst + q * 8) = o;
    }
  }
  // stage u (layer 2 only): copy X1kd[b, m, d-tile] bf16 -> u_lds[m][128]
  if (!UF32) {
    const int m = t >> 2, seg = t & 3;
    const unsigned short* src = Ubf + ((b << 6) + m) * 512 + d0 + (seg << 5);
    unsigned short* dst = u_lds + (m << 7) + (seg << 5);
    #pragma unroll
    for (int q = 0; q < 4; ++q)
      *(u16x8*)(dst + q * 8) = *(const u16x8*)(src + q * 8);
  }

  // issue W chunk 0 (m = 0..7 of this kq): linear 16 KB
  const unsigned short* Wsrc = Wt + kq * 1024;  // k-range offset within each m-slice
  #pragma unroll
  for (int j = 0; j < 4; ++j) {
    const int idx = j * 256 + t;                // unit of 8 shorts
    const int mm = idx >> 7, wi = idx & 127;
    gll16(Wsrc + mm * 4096 + wi * 8, wbuf + idx * 8);
  }
  __builtin_amdgcn_sched_barrier(0);
  asm volatile("s_waitcnt vmcnt(0) lgkmcnt(0)" ::: "memory");
  __builtin_amdgcn_sched_barrier(0);
  __builtin_amdgcn_s_barrier();
  __builtin_amdgcn_sched_barrier(0);

  // B fragments from v_lds: Bf[dt][h][jj] = v[h*32+lg*8+jj][dw*32+dt*16+l15]
  bf16x8 Bf[2][2];
  #pragma unroll
  for (int dt = 0; dt < 2; ++dt)
    #pragma unroll
    for (int h = 0; h < 2; ++h) {
      bf16x8 o;
      #pragma unroll
      for (int jj = 0; jj < 8; ++jj)
        o[jj] = (short)v_lds[((h * 32 + lg * 8 + jj) << 7) + dw * 32 + dt * 16 + l15];
      Bf[dt][h] = o;
    }

  // A-frag offsets within an m-slice (1024 shorts = 16k x 64n, XOR swizzled)
  const int kx = l15 & 7;
  const int aoff0 = l15 * 64 + ((0 + lg) ^ kx) * 8;
  const int aoff1 = l15 * 64 + ((4 + lg) ^ kx) * 8;
  const int ubase = dw * 32 + l15;

  f32x4 acc0 = {0.f, 0.f, 0.f, 0.f}, acc1 = {0.f, 0.f, 0.f, 0.f};

  for (int c = 0; c < 8; ++c) {
    if (c < 7) {  // issue chunk c+1 into the other buffer
      const unsigned short* ws = Wsrc + (c + 1) * 8 * 4096;
      unsigned short* dst = wbuf + ((c + 1) & 1) * 8192;
      #pragma unroll
      for (int j = 0; j < 4; ++j) {
        const int idx = j * 256 + t;
        const int mm = idx >> 7, wi = idx & 127;
        gll16(ws + mm * 4096 + wi * 8, dst + idx * 8);
      }
    }
    const unsigned short* bufc = wbuf + (c & 1) * 8192;
    #pragma unroll
    for (int mm = 0; mm < 8; ++mm) {
      const int m = (c << 3) + mm;
      bf16x8 a0 = *(const bf16x8*)(bufc + mm * 1024 + aoff0);
      bf16x8 a1 = *(const bf16x8*)(bufc + mm * 1024 + aoff1);
      f32x4 t0 = {0.f, 0.f, 0.f, 0.f}, t1 = {0.f, 0.f, 0.f, 0.f};
      t0 = __builtin_amdgcn_mfma_f32_16x16x32_bf16(a0, Bf[0][0], t0, 0, 0, 0);
      t0 = __builtin_amdgcn_mfma_f32_16x16x32_bf16(a1, Bf[0][1], t0, 0, 0, 0);
      t1 = __builtin_amdgcn_mfma_f32_16x16x32_bf16(a0, Bf[1][0], t1, 0, 0, 0);
      t1 = __builtin_amdgcn_mfma_f32_16x16x32_bf16(a1, Bf[1][1], t1, 0, 0, 0);
      const float u0 = bf2f(u_lds[(m << 7) + ubase]);
      const float u1 = bf2f(u_lds[(m << 7) + ubase + 16]);
      #pragma unroll
      for (int r = 0; r < 4; ++r) {
        acc0[r] += u0 * t0[r];
        acc1[r] += u1 * t1[r];
      }
    }
    if (c < 7) {
      __builtin_amdgcn_sched_barrier(0);
      asm volatile("s_waitcnt vmcnt(0)" ::: "memory");  // chunk c+1 landed
      __builtin_amdgcn_sched_barrier(0);
      __builtin_amdgcn_s_barrier();
      __builtin_amdgcn_sched_barrier(0);
    }
  }

  // epilogue: relu -> Okd[b][k][d]; k = kq*16 + lg*4 + r, d = d0 + dw*32 + dt*16 + l15
  #pragma unroll
  for (int dt = 0; dt < 2; ++dt) {
    const f32x4 a = dt ? acc1 : acc0;
    #pragma unroll
    for (int r = 0; r < 4; ++r) {
      const int k = kq * 16 + lg * 4 + r;
      const int d = d0 + dw * 32 + dt * 16 + l15;
      Okd[((b << 6) + k) * 512 + d] = f2bf(fmaxf(a[r], 0.f));
    }
  }
}

// out[b,p,d] = LN_d( x[b,p,d] + pb[p] + sum_t pw[p,t]*X1kd[b][t][d] + pw[p,64+t]*X2kd[b][t][d] )
// grid 512 = (b, 16 groups of 4 p); 512 threads = d. 2 blocks/CU.
__global__ __launch_bounds__(512) void proj_ln(
    const float* __restrict__ x, const unsigned short* __restrict__ X1kd,
    const unsigned short* __restrict__ X2kd, const float* __restrict__ pw,
    const float* __restrict__ pb, const float* __restrict__ gamma,
    const float* __restrict__ beta, float* __restrict__ out) {
  const int b = blockIdx.x >> 4, pg = blockIdx.x & 15;
  const int d = threadIdx.x;
  __shared__ float red[4 * 16];

  float s[4] = {0.f, 0.f, 0.f, 0.f};
  const float* pwb = pw + pg * 4 * 128;  // block-uniform rows
  const unsigned short* r1 = X1kd + (b << 6) * 512 + d;
  const unsigned short* r2 = X2kd + (b << 6) * 512 + d;

  #pragma unroll 4
  for (int tt = 0; tt < 64; ++tt) {
    const float c = bf2f(r1[tt * 512]);
    #pragma unroll
    for (int pi = 0; pi < 4; ++pi) s[pi] += pwb[pi * 128 + tt] * c;
  }
  #pragma unroll 4
  for (int tt = 0; tt < 64; ++tt) {
    const float c = bf2f(r2[tt * 512]);
    #pragma unroll
    for (int pi = 0; pi < 4; ++pi) s[pi] += pwb[pi * 128 + 64 + tt] * c;
  }

  const int wv = d >> 6, ln = d & 63;
  float yv[4];
  #pragma unroll
  for (int pi = 0; pi < 4; ++pi) {
    const int p = pg * 4 + pi;
    const float y = x[((b << 6) + p) * 512 + d] + pb[p] + s[pi];
    yv[pi] = y;
    float sm = y, sq = y * y;
    #pragma unroll
    for (int off = 32; off > 0; off >>= 1) {
      sm += __shfl_xor(sm, off);
      sq += __shfl_xor(sq, off);
    }
    if (ln == 0) { red[pi * 16 + wv] = sm; red[pi * 16 + 8 + wv] = sq; }
  }
  __syncthreads();

  const float gam = gamma[d], bet = beta[d];
  #pragma unroll
  for (int pi = 0; pi < 4; ++pi) {
    float sum = 0.f, sumsq = 0.f;
    #pragma unroll
    for (int j = 0; j < 8; ++j) { sum += red[pi * 16 + j]; sumsq += red[pi * 16 + 8 + j]; }
    const float mu = sum * (1.f / 512.f);
    const float var = sumsq * (1.f / 512.f) - mu * mu;
    const float rs = rsqrtf(var + 1e-5f);
    const int p = pg * 4 + pi;
    out[((b << 6) + p) * 512 + d] = gam * (yv[pi] - mu) * rs + bet;
  }
}

extern "C" void kernel_launch(void* const* d_in, const int* in_sizes, int n_in,
                              void* d_out, int out_size, void* d_ws, size_t ws_size,
                              hipStream_t stream) {
  const float* x     = (const float*)d_in[0];
  const float* W1    = (const float*)d_in[1];
  const float* W2    = (const float*)d_in[2];
  const float* pw    = (const float*)d_in[3];
  const float* pb    = (const float*)d_in[4];
  const float* gamma = (const float*)d_in[5];
  const float* beta  = (const float*)d_in[6];
  float* out = (float*)d_out;

  char* ws = (char*)d_ws;
  unsigned short* X1kd = (unsigned short*)(ws);                          // 2MB [32][64][512]
  unsigned short* X2kd = (unsigned short*)(ws + (2u << 20));             // 2MB [32][64][512]
  unsigned short* W1t  = (unsigned short*)(ws + (4u << 20));             // 512KB swz
  unsigned short* W2t  = (unsigned short*)(ws + (4u << 20) + (512u << 10));

  transpose_w<<<dim3(128), dim3(256), 0, stream>>>(W1, W2, W1t, W2t);
  // layer 1: u = v = x (alias inside), LDS = 32KB wbuf + 16KB v = 48KB
  layer_k16<1><<<dim3(512), dim3(256), 49152, stream>>>(nullptr, x, W1t, X1kd);
  // layer 2: u = relu(X1) bf16, LDS = 32 + 16 + 16 = 64KB
  layer_k16<0><<<dim3(512), dim3(256), 65536, stream>>>(X1kd, x, W2t, X2kd);
  proj_ln<<<dim3(512), dim3(512), 0, stream>>>(x, X1kd, X2kd, pw, pb, gamma, beta, out);
}